// Round 18
// baseline (91.851 us; speedup 1.0000x reference)
//
#include <hip/hip_runtime.h>
#include <math.h>

// Problem constants: B=4, C=128, H=W=96, E=4, C8=16, scale=2 (baked in)
#define Bn 4
#define Cc 128
#define Hh 96
#define Ww 96
#define H2c 192
#define W2c 192
#define HW (Hh*Ww)
#define HW2 (H2c*W2c)

// Workspace: floats [0,16) = per-class taps {tx,ty,Dx,Dy};
//            ushort Mw at float-offset 16: M[cls][c_out][128] (We*Wc + I, bf16)
#define TAP_OFF 0
#define M_OFF 16

typedef float  f32x4  __attribute__((ext_vector_type(4)));
typedef short  s16x8  __attribute__((ext_vector_type(8)));

__device__ __forceinline__ unsigned f2bf(float f) {
    unsigned u = __float_as_uint(f);
    return (u + 0x7FFFu + ((u >> 16) & 1u)) >> 16;   // RNE to bf16
}

// global -> LDS DMA, 16B per lane. LDS dest = wave-uniform base + lane*16.
__device__ __forceinline__ void gload_lds16(const float* g, float* l) {
    __builtin_amdgcn_global_load_lds(
        (const __attribute__((address_space(1))) unsigned int*)g,
        (__attribute__((address_space(3))) unsigned int*)l, 16, 0, 0);
}

// ---------------------------------------------------------------------------
// K1 (fused, verified r15-r17): per-class MLP -> taps AND
// M[cls] = We_mix*Wc_mix + I from GLOBAL wcomp/wexp. 64 blocks x 256 threads.
__global__ __launch_bounds__(256) void k1_prep(
    const float* __restrict__ wcomp, const float* __restrict__ wexp,
    const float* __restrict__ bw1, const float* __restrict__ bb1,
    const float* __restrict__ bw2, const float* __restrict__ bb2,
    const float* __restrict__ rw,  const float* __restrict__ rb,
    const float* __restrict__ ow,  const float* __restrict__ ob,
    float* __restrict__ ws, unsigned short* __restrict__ Mw)
{
    __shared__ float e1[64], e2[64], rr4[4], of2[2];
    const int tid   = threadIdx.x;
    const int cls   = blockIdx.x >> 4;
    const int chunk = blockIdx.x & 15;
    const float chv = (cls & 2) ? 0.25f : -0.25f;
    const float cwv = (cls & 1) ? 0.25f : -0.25f;

    if (tid < 64) {
        float h = bw1[tid*3+0]*0.5f + bw1[tid*3+1]*chv + bw1[tid*3+2]*cwv + bb1[tid];
        e1[tid] = fmaxf(h, 0.f);
    }
    __syncthreads();
    if (tid < 64) {
        float s = bb2[tid];
        for (int i = 0; i < 64; ++i) s += bw2[tid*64+i]*e1[i];
        e2[tid] = fmaxf(s, 0.f);
    }
    __syncthreads();
    if (tid < 6) {
        if (tid < 4) {
            float s = rb[tid];
            for (int i = 0; i < 64; ++i) s += rw[tid*64+i]*e2[i];
            rr4[tid] = 1.f/(1.f+expf(-s));
        } else {
            const int d = tid - 4;
            float s = ob[d];
            for (int i = 0; i < 64; ++i) s += ow[d*64+i]*e2[i];
            of2[d] = s;
        }
    }
    __syncthreads();
    const float r0 = rr4[0], r1 = rr4[1], r2 = rr4[2], r3 = rr4[3];

    if (chunk == 0 && tid == 0) {
        const float fx = cwv + of2[0];
        const float fy = chv + of2[1];
        const float Dx = floorf(fx), Dy = floorf(fy);
        ws[TAP_OFF + cls*4 + 0] = fx - Dx;
        ws[TAP_OFF + cls*4 + 1] = fy - Dy;
        ws[TAP_OFF + cls*4 + 2] = Dx;
        ws[TAP_OFF + cls*4 + 3] = Dy;
    }

    // M slice: thread -> (co, ci0..+3). wexp[e][c][o]: e*2048+c*16+o;
    // wcomp[e][o][c]: e*2048+o*128+c.
    const int co  = chunk*8 + (tid >> 5);
    const int ci0 = (tid & 31) * 4;
    const float* weB = wexp + co*16;
    float wem[16];
    #pragma unroll
    for (int o = 0; o < 16; ++o)
        wem[o] = r0*weB[o] + r1*weB[2048+o] + r2*weB[4096+o] + r3*weB[6144+o];
    float m[4];
    #pragma unroll
    for (int q = 0; q < 4; ++q) {
        const int ci = ci0 + q;
        const float* wcB = wcomp + ci;
        float s = 0.f;
        #pragma unroll
        for (int o = 0; o < 16; ++o) {
            const float wcm = r0*wcB[o*128]        + r1*wcB[2048 + o*128]
                            + r2*wcB[4096 + o*128] + r3*wcB[6144 + o*128];
            s += wem[o]*wcm;
        }
        if (co == ci) s += 1.f;
        m[q] = s;
    }
    uint2 v;
    v.x = f2bf(m[0]) | (f2bf(m[1]) << 16);
    v.y = f2bf(m[2]) | (f2bf(m[3]) << 16);
    *reinterpret_cast<uint2*>(Mw + (size_t)cls*16384 + co*128 + ci0) = v;
}

// Edge remap (verified rounds 1-17).
__device__ __forceinline__ void remap_axis(int c0, int last, float w0, float w1,
                                           int& base, float& a0, float& a1)
{
    base = min(max(c0, 0), last - 1);
    if (c0 >= 0 && c0 < last) { a0 = w0;  a1 = w1;  }
    else if (c0 == -1)        { a0 = w1;  a1 = 0.f; }
    else if (c0 == last)      { a0 = 0.f; a1 = w0;  }
    else                      { a0 = 0.f; a1 = 0.f; }
}

// ---------------------------------------------------------------------------
// K2: FULL-ROW blocks, dense contiguous staging, slice-pipelined MFMA.
// 768 blocks x 256 threads. Block = one full-res row yg (192 px, both
// x-parities) x 128 ch. Key fact: a channel's 3-row full-width window
// (rows jDc..jDc+2) is CONTIGUOUS (288 floats) -> staged as dense 1KB
// global_load_lds instrs (the 6.3 TB/s pattern). Per 32-ch K-slice:
// stage(36KB, prefetched under prev MFMA) -> produce fea[192][32] bf16 ->
// 24 MFMA/wave (r13's verified swapped-operand scheme, class-pure tiles).
__global__ __launch_bounds__(256) void k2_row(
    const float* __restrict__ x, const float* __restrict__ wsr,
    const unsigned short* __restrict__ Mw, float* __restrict__ out)
{
    __shared__ __align__(16) float xrA[16*288];            // 18 KB
    __shared__ __align__(16) float xrB[16*288];            // 18 KB
    __shared__ __align__(16) unsigned short feaS[192*32];  // 12 KB (swizzled)

    const int tid = threadIdx.x;
    const int xl  = tid & 63;
    const int wv  = tid >> 6;

    // XCD swizzle: 768 = 8 XCDs * 96; each XCD gets 96 consecutive rows of
    // one batch (adjacent yg share window rows in L2).
    const int n  = blockIdx.x;
    const int w  = (n & 7)*96 + (n >> 3);
    const int b  = w / 192;
    const int yg = w % 192;
    const int ygp = yg & 1;
    const int j   = yg >> 1;          // half-res row
    const int clsE = ygp << 1;        // even-x class; odd = clsE|1

    // taps for this row's two classes
    const float txE = wsr[TAP_OFF + clsE*4 + 0], txO = wsr[TAP_OFF + (clsE|1)*4 + 0];
    const float tyE = wsr[TAP_OFF + clsE*4 + 1], tyO = wsr[TAP_OFF + (clsE|1)*4 + 1];
    const int   DxE = (int)wsr[TAP_OFF + clsE*4 + 2], DxO = (int)wsr[TAP_OFF + (clsE|1)*4 + 2];
    const int   DyE = (int)wsr[TAP_OFF + clsE*4 + 3], DyO = (int)wsr[TAP_OFF + (clsE|1)*4 + 3];

    const int minDy = min(DyE, DyO);
    const int jDc   = min(max(j + minDy, 0), Hh - 3);     // rows jDc..jDc+2
    const float* xsrc = x + (size_t)b*Cc*HW + (size_t)jDc*Ww;

    // ---- producer per-thread setup (slot = tid for tid<192) ----
    // slot s: pxp = s>=96, i = s%96, cls = clsE|pxp, xg = 2i+pxp.
    const int slot = tid;
    const int pxp  = (slot >= 96) ? 1 : 0;
    const int i    = slot - pxp*96;
    const float tx = pxp ? txO : txE;
    const float ty = pxp ? tyO : tyE;
    const int   Dx = pxp ? DxO : DxE;
    const int   Dy = pxp ? DyO : DyE;
    int basex, basey; float ax0, ax1, ay0, ay1;
    remap_axis(i + Dx, Ww - 1, 1.f - tx, tx, basex, ax0, ax1);
    remap_axis(j + Dy, Hh - 1, 1.f - ty, ty, basey, ay0, ay1);
    const float w00 = ay0*ax0, w01 = ay0*ax1, w10 = ay1*ax0, w11 = ay1*ax1;
    const int ro = (basey - jDc)*Ww + basex;   // in [0,287], ro+97 <= 287+... ok

    // dense DMA: half h (16 ch) = 4608 floats = 18 x 1KB instrs; wave wv
    // issues k = wv, wv+4, ... ; lane l covers floats [k*256+l*4, +4).
#define ISSUE_DMA(S) { \
    _Pragma("unroll") \
    for (int h = 0; h < 2; ++h) { \
        float* dstb = h ? xrB : xrA; \
        for (int k = wv; k < 18; k += 4) { \
            const int f  = k*256 + xl*4; \
            const int ch = f / 288; \
            const int off = f - ch*288; \
            gload_lds16(xsrc + (size_t)((S)*32 + h*16 + ch)*HW + off, dstb + k*256); \
        } \
    } }

    ISSUE_DMA(0)

    f32x4 acc[3][8];
    #pragma unroll
    for (int t = 0; t < 3; ++t)
        #pragma unroll
        for (int c = 0; c < 8; ++c) acc[t][c] = (f32x4){0.f,0.f,0.f,0.f};

    const int lo = xl & 15, hi = xl >> 4;
    const int clsW = (wv < 2) ? clsE : (clsE | 1);       // wave's tile class
    const unsigned short* McW = Mw + (size_t)clsW*16384;

    for (int s = 0; s < 4; ++s) {
        __syncthreads();             // drains vmcnt: slice-s staging visible
        if (tid < 192) {
            #pragma unroll
            for (int q = 0; q < 8; ++q) {       // 4 ch per q
                float f[4];
                #pragma unroll
                for (int u = 0; u < 4; ++u) {
                    const int c2 = q*4 + u;     // slice-local ch 0..31
                    const float* xr = (c2 < 16) ? (xrA + (c2)*288)
                                                : (xrB + (c2-16)*288);
                    f[u] = w00*xr[ro] + w01*xr[ro+1] + w10*xr[ro+Ww] + w11*xr[ro+Ww+1];
                }
                uint2 v;
                v.x = f2bf(f[0]) | (f2bf(f[1]) << 16);
                v.y = f2bf(f[2]) | (f2bf(f[3]) << 16);
                int byte = slot*64 + q*8;
                byte ^= (slot & 7) << 4;
                *reinterpret_cast<uint2*>(reinterpret_cast<char*>(feaS) + byte) = v;
            }
        }
        __syncthreads();             // fea(s) visible; xr reads done
        if (s < 3) ISSUE_DMA(s+1)    // prefetch next slice under MFMA

        // B-frags for this slice: col = co = cot*16+lo, k = s*32 + hi*8
        s16x8 mf[8];
        #pragma unroll
        for (int cot = 0; cot < 8; ++cot)
            mf[cot] = *reinterpret_cast<const s16x8*>(
                McW + (cot*16 + lo)*128 + s*32 + hi*8);

        #pragma unroll
        for (int tt = 0; tt < 3; ++tt) {
            const int row = (3*wv + tt)*16 + lo;          // fea slot (A row)
            int byte = row*64 + hi*16;
            byte ^= (row & 7) << 4;
            const s16x8 af = *reinterpret_cast<const s16x8*>(
                reinterpret_cast<const char*>(feaS) + byte);
            #pragma unroll
            for (int cot = 0; cot < 8; ++cot)
                acc[tt][cot] = __builtin_amdgcn_mfma_f32_16x16x32_bf16(
                    af, mf[cot], acc[tt][cot], 0, 0, 0);
        }
        // loop-top __syncthreads orders fea reads before next produce
    }

    // ---- stores (r13-proven pattern): D row = slot-in-tile, col = ch ----
    float* rowbase = out + ((size_t)(b*Cc)*H2c + yg)*W2c;
    #pragma unroll
    for (int tt = 0; tt < 3; ++tt) {
        #pragma unroll
        for (int r = 0; r < 4; ++r) {
            const int slot2 = (3*wv + tt)*16 + hi*4 + r;
            const int pxp2  = (slot2 >= 96) ? 1 : 0;
            const int xg    = 2*(slot2 - pxp2*96) + pxp2;
            #pragma unroll
            for (int cot = 0; cot < 8; ++cot) {
                const int ch = cot*16 + lo;
                rowbase[(size_t)ch*HW2 + xg] = acc[tt][cot][r];
            }
        }
    }
}

extern "C" void kernel_launch(void* const* d_in, const int* in_sizes, int n_in,
                              void* d_out, int out_size, void* d_ws, size_t ws_size,
                              hipStream_t stream) {
    const float* x     = (const float*)d_in[0];
    const float* wcomp = (const float*)d_in[1];
    const float* wexp  = (const float*)d_in[2];
    const float* bw1   = (const float*)d_in[3];
    const float* bb1   = (const float*)d_in[4];
    const float* bw2   = (const float*)d_in[5];
    const float* bb2   = (const float*)d_in[6];
    const float* rw    = (const float*)d_in[7];
    const float* rb    = (const float*)d_in[8];
    const float* ow    = (const float*)d_in[9];
    const float* ob    = (const float*)d_in[10];
    float* out = (float*)d_out;
    float* ws  = (float*)d_ws;
    unsigned short* Mw = (unsigned short*)(ws + M_OFF);   // ~128 KB used

    k1_prep<<<64, 256, 0, stream>>>(wcomp, wexp, bw1, bb1, bw2, bb2,
                                    rw, rb, ow, ob, ws, Mw);
    k2_row<<<768, 256, 0, stream>>>(x, ws, Mw, out);
}